// Round 4
// baseline (434.720 us; speedup 1.0000x reference)
//
#include <hip/hip_runtime.h>
#include <hip/hip_bf16.h>
#include <stdint.h>

typedef __bf16 bf16_t;
typedef __bf16 bf16x8 __attribute__((ext_vector_type(8)));
typedef float  f32x4  __attribute__((ext_vector_type(4)));
typedef float  f32x4u __attribute__((ext_vector_type(4), aligned(4)));
typedef float  f32x2u __attribute__((ext_vector_type(2), aligned(4)));

constexpr int kOH = 222, kOW = 222;
constexpr int kS    = kOH * kOW;       // 49284 positions per (b,c) plane
constexpr int kCin  = 32, kH = 224, kW = 224;
constexpr int kCout = 64;
constexpr int kKdim = 288;             // tap-major K: k' = tap*32 + t
constexpr int kB    = 16;
constexpr int kM    = kB * kS;         // 788544 output rows
constexpr int kBM   = 64;              // rows per tile
constexpr int kT    = 3;               // tiles per block (788544 = 4107*192)
constexpr int kTapBytes = kBM * 32 * 2;  // 4096 B per tap plane in LDS

// weights fp32 [288][64] -> wt bf16 [64][288], K reordered tap-major:
// wt[n*288 + tap*32 + t] = w[(t*9 + tap)*64 + n]
__global__ void prep_weights(const float* __restrict__ w, bf16_t* __restrict__ wt) {
    int e = blockIdx.x * 256 + threadIdx.x;
    if (e >= kCout * kKdim) return;
    int n  = e / kKdim, kp = e - n * kKdim;
    int tap = kp >> 5, t = kp & 31;
    wt[e] = (bf16_t)w[(t * 9 + tap) * kCout + n];
}

// register-staged tile state (T14 async-STAGE split: issue early, write late)
struct Stage {
    f32x4u v0[3], v1[3];   // cols jj+0..3, jj+4..7 per tap-row
    f32x2u v2[3];          // cols jj+8..9
    f32x2u vx[3];          // cols jj+10..11 (loaded only on row-wrap)
    const float* xb;
    int  E;
    bool wrap, cwrap;
};

__global__ __launch_bounds__(256, 3) void conv_mfma(
        const float* __restrict__ x, const bf16_t* __restrict__ wt,
        const float* __restrict__ bias, float* __restrict__ out) {
    // [tap][row][32] bf16, 64 B rows, XOR-swizzled 16 B slots
    __shared__ __align__(16) bf16_t sA[9 * kBM * 32];

    const int tid  = threadIdx.x;
    const int r    = tid >> 2;          // staging row in tile (0..63)
    const int g    = tid & 3;           // position-group (t0 = g*8)
    const int t0   = g * 8;
    const int wv   = tid >> 6;
    const int nh   = wv & 1;            // n-half (32 of 64 Cout)
    const int ph   = wv >> 1;           // pixel-half (32 of 64 rows)
    const int lane = tid & 63;
    const int lc   = lane & 15;
    const int q    = lane >> 4;
    const int m0   = blockIdx.x * (kBM * kT);

    // swizzled LDS write base: slot = g ^ ((r>>1)&3)
    char* wptr = (char*)sA + r * 64 + ((g ^ ((r >> 1) & 3)) << 4);

    // ---- weights: 2 n-tiles x 9 taps per wave (global, L2-hot) ----
    bf16x8 afr[2][9];
    #pragma unroll
    for (int nt = 0; nt < 2; ++nt)
        #pragma unroll
        for (int ks = 0; ks < 9; ++ks)
            afr[nt][ks] = *(const bf16x8*)(wt + (nh * 32 + nt * 16 + lc) * kKdim + ks * 32 + q * 8);

    f32x4 bv4[2];
    #pragma unroll
    for (int nt = 0; nt < 2; ++nt)
        bv4[nt] = *(const f32x4*)(bias + nh * 32 + nt * 16 + q * 4);

    Stage st;
    // ---- issue global loads for a tile (reg-staged prefetch) ----
    auto issue = [&](int tm0) {
        int m  = tm0 + r;
        int b  = m / kS;
        int s  = m - b * kS;
        int P0 = s * 32 + t0;           // linear (c,pp) position
        int c  = P0 / kS;
        int pp = P0 - c * kS;
        int ii = pp / kOW;
        int jj = pp - ii * kOW;
        const float* xb = x + (((b * kCin + c) * kH) + ii) * kW + jj;
        st.xb    = xb;
        st.wrap  = (jj > kOW - 8);
        st.cwrap = st.wrap && (ii == kOW - 1);
        st.E     = kOW - jj;
        #pragma unroll
        for (int di = 0; di < 3; ++di) {
            const float* pr = xb + di * kW;
            st.v0[di] = *(const f32x4u*)pr;
            st.v1[di] = *(const f32x4u*)(pr + 4);
            st.v2[di] = *(const f32x2u*)(pr + 8);
        }
        if (st.wrap && !st.cwrap) {
            // row-wrap: +2 shift stays inside a 12-col window; cols jj+10..11
            // stay in-plane (ii<221), so this never runs past the tensor.
            #pragma unroll
            for (int di = 0; di < 3; ++di)
                st.vx[di] = *(const f32x2u*)(st.xb + di * kW + 10);
        } else {
            #pragma unroll
            for (int di = 0; di < 3; ++di) st.vx[di] = f32x2u{0.0f, 0.0f};
        }
    };

    // ---- cvt-once + bf16 select + swizzled LDS write ----
    auto stage_lds = [&]() {
        bool me[8];
        #pragma unroll
        for (int e = 0; e < 8; ++e) me[e] = st.wrap && (e >= st.E);
        #pragma unroll
        for (int di = 0; di < 3; ++di) {
            float a[12];
            a[0] = st.v0[di][0]; a[1] = st.v0[di][1];
            a[2] = st.v0[di][2]; a[3] = st.v0[di][3];
            a[4] = st.v1[di][0]; a[5] = st.v1[di][1];
            a[6] = st.v1[di][2]; a[7] = st.v1[di][3];
            a[8] = st.v2[di][0]; a[9] = st.v2[di][1];
            a[10] = st.vx[di][0]; a[11] = st.vx[di][1];
            bf16_t c16[12];
            #pragma unroll
            for (int k = 0; k < 12; ++k) c16[k] = (bf16_t)a[k];
            if (st.cwrap) {
                // channel wrap: wrapped selects read only c16[k], k>=E+2;
                // unwrapped only k<=E+1 -> disjoint, safe to overwrite.
                const float* pw = st.xb + di * kW + (2 + 2 * kW);
                #pragma unroll
                for (int k = 3; k < 12; ++k)
                    if (k >= st.E + 2) c16[k] = (bf16_t)pw[k - 2];
            }
            #pragma unroll
            for (int dj = 0; dj < 3; ++dj) {
                bf16x8 bv;
                #pragma unroll
                for (int e = 0; e < 8; ++e)
                    bv[e] = me[e] ? c16[dj + e + 2] : c16[dj + e];
                *(bf16x8*)(wptr + (di * 3 + dj) * kTapBytes) = bv;
            }
        }
    };

    issue(m0);                                  // prologue prefetch

    for (int t = 0; t < kT; ++t) {
        stage_lds();                            // waits on loads(t) here
        __syncthreads();
        if (t + 1 < kT) issue(m0 + (t + 1) * kBM);   // prefetch next tile

        // ---- MFMA: wave owns (n-half, pixel-half); B reused across n-tiles ----
        f32x4 acc[2][2] = {};
        #pragma unroll
        for (int pgl = 0; pgl < 2; ++pgl) {
            const int row = (ph * 2 + pgl) * 16 + lc;
            const char* bx = (const char*)sA + row * 64 + ((q ^ ((lc >> 1) & 3)) << 4);
            #pragma unroll
            for (int ks = 0; ks < 9; ++ks) {
                bf16x8 bfrag = *(const bf16x8*)(bx + ks * kTapBytes);
                acc[0][pgl] = __builtin_amdgcn_mfma_f32_16x16x32_bf16(afr[0][ks], bfrag, acc[0][pgl], 0, 0, 0);
                acc[1][pgl] = __builtin_amdgcn_mfma_f32_16x16x32_bf16(afr[1][ks], bfrag, acc[1][pgl], 0, 0, 0);
            }
        }

        // ---- epilogue: plain stores (L2 combines lines) ----
        const int tm0 = m0 + t * kBM;
        #pragma unroll
        for (int pgl = 0; pgl < 2; ++pgl) {
            int m = tm0 + (ph * 2 + pgl) * 16 + lc;
            int b = m / kS;
            int s = m - b * kS;
            #pragma unroll
            for (int nt = 0; nt < 2; ++nt) {
                float* op = out + (b * kCout + nh * 32 + nt * 16 + q * 4) * kS + s;
                #pragma unroll
                for (int reg = 0; reg < 4; ++reg)
                    op[reg * kS] = acc[nt][pgl][reg] + bv4[nt][reg];
            }
        }
        __syncthreads();                        // sA reusable next iter
    }
}

extern "C" void kernel_launch(void* const* d_in, const int* in_sizes, int n_in,
                              void* d_out, int out_size, void* d_ws, size_t ws_size,
                              hipStream_t stream) {
    (void)in_sizes; (void)n_in; (void)out_size; (void)ws_size;
    const float* x    = (const float*)d_in[0];
    const float* w    = (const float*)d_in[1];
    const float* bias = (const float*)d_in[2];
    float*       out  = (float*)d_out;
    bf16_t*      wt   = (bf16_t*)d_ws;   // 64*288*2 = 36864 B

    prep_weights<<<(kCout * kKdim + 255) / 256, 256, 0, stream>>>(w, wt);
    conv_mfma<<<kM / (kBM * kT), 256, 0, stream>>>(x, wt, bias, out);
}

// Round 5
// 346.397 us; speedup vs baseline: 1.2550x; 1.2550x over previous
//
#include <hip/hip_runtime.h>
#include <hip/hip_bf16.h>
#include <stdint.h>

typedef __bf16 bf16_t;
typedef __bf16 bf16x8 __attribute__((ext_vector_type(8)));
typedef float  f32x4  __attribute__((ext_vector_type(4)));
typedef float  f32x4u __attribute__((ext_vector_type(4), aligned(4)));
typedef float  f32x2u __attribute__((ext_vector_type(2), aligned(4)));

constexpr int kOH = 222, kOW = 222;
constexpr int kS    = kOH * kOW;       // 49284 positions per (b,c) plane
constexpr int kCin  = 32, kH = 224, kW = 224;
constexpr int kCout = 64;
constexpr int kKdim = 288;             // tap-major K: k' = tap*32 + t
constexpr int kB    = 16;
constexpr int kM    = kB * kS;         // 788544 output rows
constexpr int kBM   = 64;              // rows per block-tile (16 per wave)
constexpr int kT    = 3;               // tiles per block (788544 = 4107*192)
constexpr int kLW   = 576;             // LDS bytes per weight row (288 bf16)

// weights fp32 [288][64] -> wt bf16 [64][288], K reordered tap-major:
// wt[n*288 + tap*32 + t] = w[(t*9 + tap)*64 + n]
__global__ void prep_weights(const float* __restrict__ w, bf16_t* __restrict__ wt) {
    int e = blockIdx.x * 256 + threadIdx.x;
    if (e >= kCout * kKdim) return;
    int n  = e / kKdim, kp = e - n * kKdim;
    int tap = kp >> 5, t = kp & 31;
    wt[e] = (bf16_t)w[(t * 9 + tap) * kCout + n];
}

// register-staged pixel window (T14: issue early, consume late)
struct Stage {
    f32x4u v0[3], v1[3];   // cols jj+0..3, jj+4..7 per tap-row
    f32x2u v2[3];          // cols jj+8..9
    f32x2u vx[3];          // cols jj+10..11 (loaded only on row-wrap)
    const float* xb;
    int  E;
    bool wrap, cwrap;
};

__global__ __launch_bounds__(256, 4) void conv_mfma(
        const float* __restrict__ x, const bf16_t* __restrict__ wt,
        const float* __restrict__ bias, float* __restrict__ out) {
    // weights only: [n(64)][ks(9)][swizzled 16B slot(4)] + 256 B bias
    __shared__ __align__(16) char sW[kCout * kLW + 256];
    float* sBias = (float*)(sW + kCout * kLW);

    const int tid  = threadIdx.x;
    const int wv   = tid >> 6;
    const int lane = tid & 63;
    const int lc   = lane & 15;        // pixel row within wave tile / weight row
    const int q    = lane >> 4;        // k-slot quarter
    const int m0   = blockIdx.x * (kBM * kT);

    Stage st;
    // ---- issue global loads for this wave's 16-row tile (per-lane window) ----
    auto issue = [&](int tm0w) {
        int m  = tm0w + lc;
        int b  = m / kS;
        int s  = m - b * kS;
        int P0 = s * 32 + q * 8;        // linear (c,pp) position (raw-reshape quirk)
        int c  = P0 / kS;
        int pp = P0 - c * kS;
        int ii = pp / kOW;
        int jj = pp - ii * kOW;
        const float* xb = x + (((b * kCin + c) * kH) + ii) * kW + jj;
        st.xb    = xb;
        st.wrap  = (jj > kOW - 8);
        st.cwrap = st.wrap && (ii == kOW - 1);
        st.E     = kOW - jj;
        #pragma unroll
        for (int di = 0; di < 3; ++di) {
            const float* pr = xb + di * kW;
            st.v0[di] = *(const f32x4u*)pr;
            st.v1[di] = *(const f32x4u*)(pr + 4);
            st.v2[di] = *(const f32x2u*)(pr + 8);
        }
        if (st.wrap && !st.cwrap) {
            // row-wrap: +2 shift inside the 12-col window; ii<221 so in-plane.
            #pragma unroll
            for (int di = 0; di < 3; ++di)
                st.vx[di] = *(const f32x2u*)(st.xb + di * kW + 10);
        } else {
            #pragma unroll
            for (int di = 0; di < 3; ++di) st.vx[di] = f32x2u{0.0f, 0.0f};
        }
    };

    // ---- cvt-once + bf16 select -> 9 B-fragments IN REGISTERS (no LDS) ----
    auto stage_regs = [&](bf16x8 (&bvs)[9]) {
        #pragma unroll
        for (int di = 0; di < 3; ++di) {
            float a[12];
            a[0] = st.v0[di][0]; a[1] = st.v0[di][1];
            a[2] = st.v0[di][2]; a[3] = st.v0[di][3];
            a[4] = st.v1[di][0]; a[5] = st.v1[di][1];
            a[6] = st.v1[di][2]; a[7] = st.v1[di][3];
            a[8] = st.v2[di][0]; a[9] = st.v2[di][1];
            a[10] = st.vx[di][0]; a[11] = st.vx[di][1];
            bf16_t c16[12];
            #pragma unroll
            for (int k2 = 0; k2 < 12; ++k2) c16[k2] = (bf16_t)a[k2];
            if (st.cwrap) {
                // channel wrap: wrapped selects read only c16[k>=E+2];
                // unwrapped only k<=E+1 -> disjoint, safe to overwrite.
                const float* pw = st.xb + di * kW + (2 + 2 * kW);
                #pragma unroll
                for (int k2 = 3; k2 < 12; ++k2)
                    if (k2 >= st.E + 2) c16[k2] = (bf16_t)pw[k2 - 2];
            }
            #pragma unroll
            for (int dj = 0; dj < 3; ++dj) {
                bf16x8 bv;
                #pragma unroll
                for (int e = 0; e < 8; ++e) {
                    bool wr = st.wrap && (e >= st.E);
                    bv[e] = wr ? c16[dj + e + 2] : c16[dj + e];
                }
                bvs[di * 3 + dj] = bv;
            }
        }
    };

    issue(m0 + wv * 16);               // tile-0 pixel loads first (long pole)

    // ---- stage weights into LDS, swizzled: addr = n*576 + ks*64 + slot*16 ----
    #pragma unroll
    for (int i = 0; i < 9; ++i) {
        int sid = i * 256 + tid;       // 2304 16B slots total
        int n   = sid / 36;
        int rem = sid - n * 36;
        int ks  = rem >> 2, qq = rem & 3;
        bf16x8 v = *(const bf16x8*)(wt + n * kKdim + ks * 32 + qq * 8);
        *(bf16x8*)(sW + n * kLW + ks * 64 + ((qq ^ ((n >> 1) & 3)) << 4)) = v;
    }
    if (tid < kCout) sBias[tid] = bias[tid];

    __syncthreads();                   // weights ready; read-only afterwards

    const int rslot = (q ^ ((lc >> 1) & 3)) << 4;  // zero-conflict read slot
    const char* wb  = sW + lc * kLW + rslot;

    for (int t = 0; t < kT; ++t) {
        bf16x8 bvs[9];
        stage_regs(bvs);                            // waits on tile-t loads
        if (t + 1 < kT) issue(m0 + (t + 1) * kBM + wv * 16);  // prefetch

        // ---- MFMA: A=weights from LDS (streamed), B=own pixels (regs) ----
        f32x4 acc[4] = {};
        #pragma unroll
        for (int ks = 0; ks < 9; ++ks) {
            #pragma unroll
            for (int nt = 0; nt < 4; ++nt) {
                bf16x8 afrag = *(const bf16x8*)(wb + nt * 16 * kLW + ks * 64);
                acc[nt] = __builtin_amdgcn_mfma_f32_16x16x32_bf16(afrag, bvs[ks], acc[nt], 0, 0, 0);
            }
        }

        // ---- epilogue: bias from LDS (broadcast), plain stores ----
        int m = m0 + t * kBM + wv * 16 + lc;
        int b = m / kS;
        int s = m - b * kS;
        float* ob = out + (b * kCout + q * 4) * kS + s;
        #pragma unroll
        for (int nt = 0; nt < 4; ++nt) {
            f32x4 bb = *(const f32x4*)(sBias + nt * 16 + q * 4);
            #pragma unroll
            for (int reg = 0; reg < 4; ++reg)
                ob[(nt * 16 + reg) * kS] = acc[nt][reg] + bb[reg];
        }
        // no __syncthreads(): waves free-run across tiles
    }
}

extern "C" void kernel_launch(void* const* d_in, const int* in_sizes, int n_in,
                              void* d_out, int out_size, void* d_ws, size_t ws_size,
                              hipStream_t stream) {
    (void)in_sizes; (void)n_in; (void)out_size; (void)ws_size;
    const float* x    = (const float*)d_in[0];
    const float* w    = (const float*)d_in[1];
    const float* bias = (const float*)d_in[2];
    float*       out  = (float*)d_out;
    bf16_t*      wt   = (bf16_t*)d_ws;   // 64*288*2 = 36864 B

    prep_weights<<<(kCout * kKdim + 255) / 256, 256, 0, stream>>>(w, wt);
    conv_mfma<<<kM / (kBM * kT), 256, 0, stream>>>(x, wt, bias, out);
}